// Round 5
// baseline (1632.260 us; speedup 1.0000x reference)
//
#include <hip/hip_runtime.h>

#define B_ 256
#define S_ 512
#define V_ 50000
#define F_ 64
#define H_ 256

typedef _Float16 f16;
typedef _Float16 f16x2 __attribute__((ext_vector_type(2)));
typedef _Float16 f16x4 __attribute__((ext_vector_type(4)));
typedef _Float16 f16x8 __attribute__((ext_vector_type(8)));
typedef float f32x4 __attribute__((ext_vector_type(4)));

__device__ __forceinline__ f16x8 cvt8(const float4 a, const float4 b) {
    f16x8 v;
    v[0] = (f16)a.x; v[1] = (f16)a.y; v[2] = (f16)a.z; v[3] = (f16)a.w;
    v[4] = (f16)b.x; v[5] = (f16)b.y; v[6] = (f16)b.z; v[7] = (f16)b.w;
    return v;
}

// tanh(x) = 1 - 2/(1+e^2x); IEEE-safe at +/-inf.
__device__ __forceinline__ float fast_tanh(float x) {
    float e = __expf(2.f * x);
    float r = __builtin_amdgcn_rcpf(e + 1.f);
    return __builtin_fmaf(-2.f, r, 1.f);
}

// ---------------------------------------------------------------------------
// K1: T[v][n] = sum_f feat[v][f] * Wih0[n][f] + (bih0[n]+bhh0[n]); f16 out.
// ---------------------------------------------------------------------------
__global__ __launch_bounds__(512) void k_vocab_proj(
    const float* __restrict__ feat, const float* __restrict__ Wih,
    const float* __restrict__ bi, const float* __restrict__ bh,
    f16* __restrict__ T)
{
    __shared__ char Wl[256 * 128];
    __shared__ char Xl[16 * 128];
    const int tid = threadIdx.x;
    {
        const int n = tid >> 1, k0 = (tid & 1) << 5;
#pragma unroll
        for (int k = k0; k < k0 + 32; k += 8) {
            float4 a = *(const float4*)(Wih + n * F_ + k);
            float4 b = *(const float4*)(Wih + n * F_ + k + 4);
            *(f16x8*)(Wl + n * 128 + (((k >> 3) ^ (n & 7)) << 4)) = cvt8(a, b);
        }
    }
    const int v0 = blockIdx.x * 16;
    {
        const int m = tid >> 5, k = (tid & 31) << 1;
        float2 a = *(const float2*)(feat + (v0 + m) * F_ + k);
        f16x2 v; v[0] = (f16)a.x; v[1] = (f16)a.y;
        *(f16x2*)(Xl + m * 128 + ((((k >> 3) ^ (m & 7)) << 4) | ((k & 7) << 1))) = v;
    }
    __syncthreads();
    const int lane = tid & 63, w = tid >> 6;
    const int q = lane & 15, g = lane >> 4;
#pragma unroll
    for (int nt = 0; nt < 2; ++nt) {
        const int n0 = w * 32 + nt * 16;
        const int nrow = n0 + q;
        float4 b1 = *(const float4*)(bi + n0 + g * 4);
        float4 b2 = *(const float4*)(bh + n0 + g * 4);
        f32x4 acc = {b1.x + b2.x, b1.y + b2.y, b1.z + b2.z, b1.w + b2.w};
#pragma unroll
        for (int kb = 0; kb < 2; ++kb) {
            f16x8 a = *(const f16x8*)(Wl + nrow * 128 + (((kb * 4 + g) ^ (nrow & 7)) << 4));
            f16x8 b = *(const f16x8*)(Xl + q * 128 + (((kb * 4 + g) ^ (q & 7)) << 4));
            acc = __builtin_amdgcn_mfma_f32_16x16x32_f16(a, b, acc, 0, 0, 0);
        }
        f16x4 o; o[0] = (f16)acc[0]; o[1] = (f16)acc[1]; o[2] = (f16)acc[2]; o[3] = (f16)acc[3];
        *(f16x4*)(T + (size_t)(v0 + q) * H_ + n0 + g * 4) = o;
    }
}

// ---------------------------------------------------------------------------
// K2: FUSED two-layer RNN. 16 WGs x 512 thr. 16 batch rows per WG; wave w
// owns n-slice [32w,32w+32) of Whh0/Wih1/Whh1 as PINNED register fragments
// (asm "+v" after one-time cvt -> compiler cannot rematerialize-from-global,
// which is what made rounds 3/4 slow: VGPR_Count 64/128 < the 192 needed).
// Per step t (one lgkm-only barrier):
//   A: h0_t     = tanh(T[idx_t] + Whh0 @ h0_{t-1})     (reads h0buf rd)
//   P: pP       = bias1 + Wih1 @ h0_{t-1}              (same ds_reads as A)
//   C: h1_{t-1} = tanh(pP + Whh1 @ h1_{t-2})           (reads h1buf rd)
// 6 independent 8-deep MFMA chains/step. h0/h1 double-buffered in LDS.
// ---------------------------------------------------------------------------
__global__ __launch_bounds__(512, 2) void k_fused(
    const f16* __restrict__ T, const int* __restrict__ idx,
    const float* __restrict__ Whh0, const float* __restrict__ Wih1,
    const float* __restrict__ bih1, const float* __restrict__ bhh1,
    const float* __restrict__ Whh1, f16* __restrict__ h1out)
{
    __shared__ char h0b[2][8192];   // [16 m][256 n f16], swizzled
    __shared__ char h1b[2][8192];
    const int tid = threadIdx.x, lane = tid & 63, w = tid >> 6;
    const int q = lane & 15, g = lane >> 4;
    const int brow = (blockIdx.x << 4) + q;
    const int ncol = w * 32;
    const int hswz = (q & 7) << 4;
    const int hrow = q * 512;

    // --- weight fragments: A=Whh0, P=Wih1, C=Whh1 (one-time load+convert) ---
    f16x8 wA[2][8], wP[2][8], wC[2][8];
#pragma unroll
    for (int tt = 0; tt < 2; ++tt) {
        const int n = ncol + tt * 16 + q;
#pragma unroll
        for (int kb = 0; kb < 8; ++kb) {
            const int o = n * H_ + kb * 32 + g * 8;
            wA[tt][kb] = cvt8(*(const float4*)(Whh0 + o), *(const float4*)(Whh0 + o + 4));
            wP[tt][kb] = cvt8(*(const float4*)(Wih1 + o), *(const float4*)(Wih1 + o + 4));
            wC[tt][kb] = cvt8(*(const float4*)(Whh1 + o), *(const float4*)(Whh1 + o + 4));
        }
    }
    // PIN: opaque volatile asm -> values must stay live; no per-step remat.
#pragma unroll
    for (int tt = 0; tt < 2; ++tt)
#pragma unroll
        for (int kb = 0; kb < 8; ++kb)
            asm volatile("" : "+v"(wA[tt][kb]), "+v"(wP[tt][kb]), "+v"(wC[tt][kb]));

    f32x4 bs1[2];
#pragma unroll
    for (int tt = 0; tt < 2; ++tt) {
        const int n = ncol + tt * 16 + g * 4;
        float4 x = *(const float4*)(bih1 + n);
        float4 y = *(const float4*)(bhh1 + n);
        bs1[tt][0] = x.x + y.x; bs1[tt][1] = x.y + y.y;
        bs1[tt][2] = x.z + y.z; bs1[tt][3] = x.w + y.w;
    }
    {   // h0_{-1}=0, h1_{-1}=0 into the buffers read first
        f32x4 z = {0.f, 0.f, 0.f, 0.f};
        *(f32x4*)(h0b[1] + tid * 16) = z;
        *(f32x4*)(h1b[1] + tid * 16) = z;
    }
    // --- input prefetch: rows 0,1 + idx 2,3 ---
    const int* idxr = idx + brow * S_;
    f16x4 xa[2], xb[2];
    {
        const size_t r0 = (size_t)idxr[0] * H_, r1 = (size_t)idxr[1] * H_;
#pragma unroll
        for (int tt = 0; tt < 2; ++tt) {
            xa[tt] = *(const f16x4*)(T + r0 + ncol + tt * 16 + g * 4);
            xb[tt] = *(const f16x4*)(T + r1 + ncol + tt * 16 + g * 4);
        }
    }
    int idA = idxr[2], idB = idxr[3];
    __syncthreads();

#define FR(buf, kb) (*(const f16x8*)((buf) + hrow + (((kb) * 64 + g * 16) ^ hswz)))
#define STEP_BAR() do { \
        asm volatile("s_waitcnt lgkmcnt(0)" ::: "memory"); \
        __builtin_amdgcn_s_barrier(); \
    } while (0)

    // one full step: A (recur0) + P (proj) + C (recur1). XV/ID rotate statically.
#define BODY(XV, ID, RD0, WR0, RD1, WR1, T_) do {                               \
        f32x4 a0[2], pP[2], pC[2];                                              \
        _Pragma("unroll")                                                       \
        for (int tt = 0; tt < 2; ++tt) {                                        \
            a0[tt][0] = (float)XV[tt][0]; a0[tt][1] = (float)XV[tt][1];         \
            a0[tt][2] = (float)XV[tt][2]; a0[tt][3] = (float)XV[tt][3];         \
            pP[tt] = bs1[tt];                                                   \
            pC[tt][0] = 0.f; pC[tt][1] = 0.f; pC[tt][2] = 0.f; pC[tt][3] = 0.f; \
        }                                                                       \
        {   /* reissue XV <- row (T_+2), reload ID <- idx[T_+4] (clamped) */    \
            const size_t rr = (size_t)ID * H_;                                  \
            _Pragma("unroll")                                                   \
            for (int tt = 0; tt < 2; ++tt)                                      \
                XV[tt] = *(const f16x4*)(T + rr + ncol + tt * 16 + g * 4);      \
            const int t4 = (T_ + 4 < S_) ? T_ + 4 : S_ - 1;                     \
            ID = idxr[t4];                                                      \
        }                                                                       \
        _Pragma("unroll")                                                       \
        for (int kb = 0; kb < 8; ++kb) {                                        \
            f16x8 bf = FR(RD0, kb);                                             \
            a0[0] = __builtin_amdgcn_mfma_f32_16x16x32_f16(wA[0][kb], bf, a0[0], 0, 0, 0); \
            a0[1] = __builtin_amdgcn_mfma_f32_16x16x32_f16(wA[1][kb], bf, a0[1], 0, 0, 0); \
            pP[0] = __builtin_amdgcn_mfma_f32_16x16x32_f16(wP[0][kb], bf, pP[0], 0, 0, 0); \
            pP[1] = __builtin_amdgcn_mfma_f32_16x16x32_f16(wP[1][kb], bf, pP[1], 0, 0, 0); \
        }                                                                       \
        _Pragma("unroll")                                                       \
        for (int tt = 0; tt < 2; ++tt) {   /* h0_t -> WR0 */                    \
            f16x4 hv;                                                           \
            _Pragma("unroll")                                                   \
            for (int r = 0; r < 4; ++r) hv[r] = (f16)fast_tanh(a0[tt][r]);      \
            const int nd = ncol + tt * 16 + g * 4;                              \
            *(f16x4*)(WR0 + hrow + ((nd * 2) ^ hswz)) = hv;                     \
        }                                                                       \
        _Pragma("unroll")                                                       \
        for (int kb = 0; kb < 8; ++kb) {                                        \
            f16x8 cf = FR(RD1, kb);                                             \
            pC[0] = __builtin_amdgcn_mfma_f32_16x16x32_f16(wC[0][kb], cf, pC[0], 0, 0, 0); \
            pC[1] = __builtin_amdgcn_mfma_f32_16x16x32_f16(wC[1][kb], cf, pC[1], 0, 0, 0); \
        }                                                                       \
        _Pragma("unroll")                                                       \
        for (int tt = 0; tt < 2; ++tt) {   /* h1_{T_-1} -> WR1 */               \
            f16x4 hv;                                                           \
            _Pragma("unroll")                                                   \
            for (int r = 0; r < 4; ++r) hv[r] = (f16)fast_tanh(pP[tt][r] + pC[tt][r]); \
            const int nd = ncol + tt * 16 + g * 4;                              \
            *(f16x4*)(WR1 + hrow + ((nd * 2) ^ hswz)) = hv;                     \
        }                                                                       \
        STEP_BAR();                                                             \
    } while (0)

    // ---- peel t=0: phase A only (h0_0), reissue xa <- row 2 ----
    {
        f32x4 a0[2];
#pragma unroll
        for (int tt = 0; tt < 2; ++tt) {
            a0[tt][0] = (float)xa[tt][0]; a0[tt][1] = (float)xa[tt][1];
            a0[tt][2] = (float)xa[tt][2]; a0[tt][3] = (float)xa[tt][3];
        }
        {
            const size_t rr = (size_t)idA * H_;
#pragma unroll
            for (int tt = 0; tt < 2; ++tt)
                xa[tt] = *(const f16x4*)(T + rr + ncol + tt * 16 + g * 4);
            idA = idxr[4];
        }
#pragma unroll
        for (int kb = 0; kb < 8; ++kb) {
            f16x8 bf = FR(h0b[1], kb);
            a0[0] = __builtin_amdgcn_mfma_f32_16x16x32_f16(wA[0][kb], bf, a0[0], 0, 0, 0);
            a0[1] = __builtin_amdgcn_mfma_f32_16x16x32_f16(wA[1][kb], bf, a0[1], 0, 0, 0);
        }
#pragma unroll
        for (int tt = 0; tt < 2; ++tt) {
            f16x4 hv;
#pragma unroll
            for (int r = 0; r < 4; ++r) hv[r] = (f16)fast_tanh(a0[tt][r]);
            const int nd = ncol + tt * 16 + g * 4;
            *(f16x4*)(h0b[0] + hrow + ((nd * 2) ^ hswz)) = hv;
        }
        STEP_BAR();
    }

    // ---- main: t = 1..510 in parity pairs ----
    for (int t = 1; t < S_ - 1; t += 2) {
        BODY(xb, idB, h0b[0], h0b[1], h1b[1], h1b[0], t);       // odd t
        BODY(xa, idA, h0b[1], h0b[0], h1b[0], h1b[1], t + 1);   // even t
    }

    // ---- peel t=511 (odd): full step, consumes xb, no reissue ----
    {
        f32x4 a0[2], pP[2], pC[2];
#pragma unroll
        for (int tt = 0; tt < 2; ++tt) {
            a0[tt][0] = (float)xb[tt][0]; a0[tt][1] = (float)xb[tt][1];
            a0[tt][2] = (float)xb[tt][2]; a0[tt][3] = (float)xb[tt][3];
            pP[tt] = bs1[tt];
            pC[tt][0] = 0.f; pC[tt][1] = 0.f; pC[tt][2] = 0.f; pC[tt][3] = 0.f;
        }
#pragma unroll
        for (int kb = 0; kb < 8; ++kb) {
            f16x8 bf = FR(h0b[0], kb);
            a0[0] = __builtin_amdgcn_mfma_f32_16x16x32_f16(wA[0][kb], bf, a0[0], 0, 0, 0);
            a0[1] = __builtin_amdgcn_mfma_f32_16x16x32_f16(wA[1][kb], bf, a0[1], 0, 0, 0);
            pP[0] = __builtin_amdgcn_mfma_f32_16x16x32_f16(wP[0][kb], bf, pP[0], 0, 0, 0);
            pP[1] = __builtin_amdgcn_mfma_f32_16x16x32_f16(wP[1][kb], bf, pP[1], 0, 0, 0);
        }
#pragma unroll
        for (int tt = 0; tt < 2; ++tt) {
            f16x4 hv;
#pragma unroll
            for (int r = 0; r < 4; ++r) hv[r] = (f16)fast_tanh(a0[tt][r]);
            const int nd = ncol + tt * 16 + g * 4;
            *(f16x4*)(h0b[1] + hrow + ((nd * 2) ^ hswz)) = hv;
        }
#pragma unroll
        for (int kb = 0; kb < 8; ++kb) {
            f16x8 cf = FR(h1b[1], kb);
            pC[0] = __builtin_amdgcn_mfma_f32_16x16x32_f16(wC[0][kb], cf, pC[0], 0, 0, 0);
            pC[1] = __builtin_amdgcn_mfma_f32_16x16x32_f16(wC[1][kb], cf, pC[1], 0, 0, 0);
        }
#pragma unroll
        for (int tt = 0; tt < 2; ++tt) {
            f16x4 hv;
#pragma unroll
            for (int r = 0; r < 4; ++r) hv[r] = (f16)fast_tanh(pP[tt][r] + pC[tt][r]);
            const int nd = ncol + tt * 16 + g * 4;
            *(f16x4*)(h1b[0] + hrow + ((nd * 2) ^ hswz)) = hv;
        }
        STEP_BAR();
    }

    // ---- peel t=512: P+C only; h1_511 -> global ----
    {
        f32x4 pP[2], pC[2];
#pragma unroll
        for (int tt = 0; tt < 2; ++tt) {
            pP[tt] = bs1[tt];
            pC[tt][0] = 0.f; pC[tt][1] = 0.f; pC[tt][2] = 0.f; pC[tt][3] = 0.f;
        }
#pragma unroll
        for (int kb = 0; kb < 8; ++kb) {
            f16x8 bf = FR(h0b[1], kb);
            pP[0] = __builtin_amdgcn_mfma_f32_16x16x32_f16(wP[0][kb], bf, pP[0], 0, 0, 0);
            pP[1] = __builtin_amdgcn_mfma_f32_16x16x32_f16(wP[1][kb], bf, pP[1], 0, 0, 0);
        }
#pragma unroll
        for (int kb = 0; kb < 8; ++kb) {
            f16x8 cf = FR(h1b[0], kb);
            pC[0] = __builtin_amdgcn_mfma_f32_16x16x32_f16(wC[0][kb], cf, pC[0], 0, 0, 0);
            pC[1] = __builtin_amdgcn_mfma_f32_16x16x32_f16(wC[1][kb], cf, pC[1], 0, 0, 0);
        }
#pragma unroll
        for (int tt = 0; tt < 2; ++tt) {
            f16x4 hv;
#pragma unroll
            for (int r = 0; r < 4; ++r) hv[r] = (f16)fast_tanh(pP[tt][r] + pC[tt][r]);
            *(f16x4*)(h1out + (size_t)brow * H_ + ncol + tt * 16 + g * 4) = hv;
        }
    }
#undef BODY
#undef STEP_BAR
#undef FR
}

// ---------------------------------------------------------------------------
// K3: out[b][v] = sum_k h1[b][k] * Wout[v][k] + bout[v].  fp32 out.
// ---------------------------------------------------------------------------
__global__ __launch_bounds__(512) void k_out(
    const f16* __restrict__ h1, const float* __restrict__ Wout,
    const float* __restrict__ bout, float* __restrict__ out)
{
    __shared__ char Hl[256 * 512];
    const int tid = threadIdx.x;
    {
        const int m = tid >> 1, half = tid & 1;
#pragma unroll
        for (int i = 0; i < 16; ++i) {
            const int blk = half * 16 + i;
            f16x8 v = *(const f16x8*)(h1 + m * H_ + blk * 8);
            *(f16x8*)(Hl + m * 512 + ((blk ^ (m & 7)) << 4)) = v;
        }
    }
    __syncthreads();
    const int lane = tid & 63, w = tid >> 6;
    const int q = lane & 15, g = lane >> 4;
    const int v0 = blockIdx.x * 80;
    f32x4 acc[5][2];
#pragma unroll
    for (int vt = 0; vt < 5; ++vt) {
        float4 bo = *(const float4*)(bout + v0 + vt * 16 + g * 4);
#pragma unroll
        for (int bt = 0; bt < 2; ++bt) {
            acc[vt][bt][0] = bo.x; acc[vt][bt][1] = bo.y;
            acc[vt][bt][2] = bo.z; acc[vt][bt][3] = bo.w;
        }
    }
#pragma unroll
    for (int kb = 0; kb < 8; ++kb) {
        f16x8 bf[2];
#pragma unroll
        for (int bt = 0; bt < 2; ++bt) {
            const int mrow = (w * 2 + bt) * 16 + q;
            bf[bt] = *(const f16x8*)(Hl + mrow * 512 + (((kb * 4 + g) ^ (mrow & 7)) << 4));
        }
#pragma unroll
        for (int vt = 0; vt < 5; ++vt) {
            const size_t vrow = v0 + vt * 16 + q;
            float4 a = *(const float4*)(Wout + vrow * H_ + kb * 32 + g * 8);
            float4 b = *(const float4*)(Wout + vrow * H_ + kb * 32 + g * 8 + 4);
            f16x8 af = cvt8(a, b);
#pragma unroll
            for (int bt = 0; bt < 2; ++bt)
                acc[vt][bt] = __builtin_amdgcn_mfma_f32_16x16x32_f16(af, bf[bt], acc[vt][bt], 0, 0, 0);
        }
    }
#pragma unroll
    for (int vt = 0; vt < 5; ++vt)
#pragma unroll
        for (int bt = 0; bt < 2; ++bt) {
            const int b = (w * 2 + bt) * 16 + q;
            const int v = v0 + vt * 16 + g * 4;
            float4 o = {acc[vt][bt][0], acc[vt][bt][1], acc[vt][bt][2], acc[vt][bt][3]};
            *(float4*)(out + (size_t)b * V_ + v) = o;
        }
}

extern "C" void kernel_launch(void* const* d_in, const int* in_sizes, int n_in,
                              void* d_out, int out_size, void* d_ws, size_t ws_size,
                              hipStream_t stream) {
    (void)in_sizes; (void)n_in; (void)out_size; (void)ws_size;
    const int*   batch = (const int*)  d_in[0];
    const float* feat  = (const float*)d_in[1];
    const float* Wih0  = (const float*)d_in[2];
    const float* Whh0  = (const float*)d_in[3];
    const float* bih0  = (const float*)d_in[4];
    const float* bhh0  = (const float*)d_in[5];
    const float* Wih1  = (const float*)d_in[6];
    const float* Whh1  = (const float*)d_in[7];
    const float* bih1  = (const float*)d_in[8];
    const float* bhh1  = (const float*)d_in[9];
    const float* Wout  = (const float*)d_in[10];
    const float* bout  = (const float*)d_in[11];
    float* out = (float*)d_out;

    f16* T  = (f16*)d_out;     // 25.6MB scratch in d_out; dead before k_out writes
    f16* h1 = (f16*)d_ws;      // 128KB: final layer-1 hidden states

    k_vocab_proj<<<dim3(V_ / 16), dim3(512), 0, stream>>>(feat, Wih0, bih0, bhh0, T);
    k_fused<<<dim3(16), dim3(512), 0, stream>>>(T, batch, Whh0, Wih1, bih1, bhh1, Whh1, h1);
    k_out<<<dim3(625), dim3(512), 0, stream>>>(h1, Wout, bout, out);
}

// Round 6
// 1123.279 us; speedup vs baseline: 1.4531x; 1.4531x over previous
//
#include <hip/hip_runtime.h>

#define B_ 256
#define S_ 512
#define V_ 50000
#define F_ 64
#define H_ 256

typedef _Float16 f16;
typedef _Float16 f16x2 __attribute__((ext_vector_type(2)));
typedef _Float16 f16x4 __attribute__((ext_vector_type(4)));
typedef _Float16 f16x8 __attribute__((ext_vector_type(8)));
typedef float f32x4 __attribute__((ext_vector_type(4)));

#define MFMA(a, b, c) __builtin_amdgcn_mfma_f32_16x16x32_f16((a), (b), (c), 0, 0, 0)

__device__ __forceinline__ f16x8 cvt8(const float4 a, const float4 b) {
    f16x8 v;
    v[0] = (f16)a.x; v[1] = (f16)a.y; v[2] = (f16)a.z; v[3] = (f16)a.w;
    v[4] = (f16)b.x; v[5] = (f16)b.y; v[6] = (f16)b.z; v[7] = (f16)b.w;
    return v;
}

// tanh(x) = 1 - 2/(1+e^2x); IEEE-safe at +/-inf.
__device__ __forceinline__ float fast_tanh(float x) {
    float e = __expf(2.f * x);
    float r = __builtin_amdgcn_rcpf(e + 1.f);
    return __builtin_fmaf(-2.f, r, 1.f);
}

// ---------------------------------------------------------------------------
// K0: zero the producer->consumer flags (must happen every launch/replay).
// ---------------------------------------------------------------------------
__global__ void k_init_flags(int* flags) {
    if (threadIdx.x < 128) flags[threadIdx.x] = 0;
}

// ---------------------------------------------------------------------------
// K1: T[v][n] = sum_f feat[v][f] * Wih0[n][f] + (bih0[n]+bhh0[n]); f16 out.
// ---------------------------------------------------------------------------
__global__ __launch_bounds__(512) void k_vocab_proj(
    const float* __restrict__ feat, const float* __restrict__ Wih,
    const float* __restrict__ bi, const float* __restrict__ bh,
    f16* __restrict__ T)
{
    __shared__ char Wl[256 * 128];
    __shared__ char Xl[16 * 128];
    const int tid = threadIdx.x;
    {
        const int n = tid >> 1, k0 = (tid & 1) << 5;
#pragma unroll
        for (int k = k0; k < k0 + 32; k += 8) {
            float4 a = *(const float4*)(Wih + n * F_ + k);
            float4 b = *(const float4*)(Wih + n * F_ + k + 4);
            *(f16x8*)(Wl + n * 128 + (((k >> 3) ^ (n & 7)) << 4)) = cvt8(a, b);
        }
    }
    const int v0 = blockIdx.x * 16;
    {
        const int m = tid >> 5, k = (tid & 31) << 1;
        float2 a = *(const float2*)(feat + (v0 + m) * F_ + k);
        f16x2 v; v[0] = (f16)a.x; v[1] = (f16)a.y;
        *(f16x2*)(Xl + m * 128 + ((((k >> 3) ^ (m & 7)) << 4) | ((k & 7) << 1))) = v;
    }
    __syncthreads();
    const int lane = tid & 63, w = tid >> 6;
    const int q = lane & 15, g = lane >> 4;
#pragma unroll
    for (int nt = 0; nt < 2; ++nt) {
        const int n0 = w * 32 + nt * 16;
        const int nrow = n0 + q;
        float4 b1 = *(const float4*)(bi + n0 + g * 4);
        float4 b2 = *(const float4*)(bh + n0 + g * 4);
        f32x4 acc = {b1.x + b2.x, b1.y + b2.y, b1.z + b2.z, b1.w + b2.w};
#pragma unroll
        for (int kb = 0; kb < 2; ++kb) {
            f16x8 a = *(const f16x8*)(Wl + nrow * 128 + (((kb * 4 + g) ^ (nrow & 7)) << 4));
            f16x8 b = *(const f16x8*)(Xl + q * 128 + (((kb * 4 + g) ^ (q & 7)) << 4));
            acc = MFMA(a, b, acc);
        }
        f16x4 o; o[0] = (f16)acc[0]; o[1] = (f16)acc[1]; o[2] = (f16)acc[2]; o[3] = (f16)acc[3];
        *(f16x4*)(T + (size_t)(v0 + q) * H_ + n0 + g * 4) = o;
    }
}

// ---------------------------------------------------------------------------
// K2: split-layer persistent RNN. 32 WGs x 512 thr (8 waves = 2/EU).
//   WGs 0-15  (producer, pair p=wg): layer-0 recurrence for batch rows
//     [16p,16p+16) PLUS the layer-1 input projection (shares the same
//     ds_reads of h0_{t-1}):  p_t = b1 + Wih1 @ h0_t  -> pbuf (f16, global).
//     Per-wave flag released (agent scope) every 4 steps.
//   WGs 16-31 (consumer, pair wg-16): layer-1 recurrence
//     h1_t = tanh(p_t + Whh1 @ h1_{t-1}), lagging the producer ~8 steps;
//     polls flags (relaxed, agent) + acquire-fence once per 4-step window.
// Weight fragments live in registers; amdgpu_waves_per_eu(2,2) pins the
// scheduler's occupancy target so it cannot rematerialize them (the r2-r5
// disease: VGPR_Count 64/128 << needed, weights reloaded from L2 per step).
// No deadlock possible: producers never wait on consumers.
// ---------------------------------------------------------------------------
__global__ __launch_bounds__(512) __attribute__((amdgpu_waves_per_eu(2, 2)))
void k_rnn_split(
    const f16* __restrict__ T, const int* __restrict__ idx,
    const float* __restrict__ Whh0, const float* __restrict__ Wih1,
    const float* __restrict__ bih1, const float* __restrict__ bhh1,
    const float* __restrict__ Whh1,
    f16* __restrict__ pbuf, int* flags, f16* __restrict__ h1out)
{
    __shared__ char hb[2][8192];   // double-buffered [16 m][256 n f16], swizzled
    const int wg = blockIdx.x;
    const int tid = threadIdx.x, lane = tid & 63, w = tid >> 6;
    const int q = lane & 15, g = lane >> 4;
    const int ncol = w * 32;
    const int hswz = (q & 7) << 4;
    const int hrow = q * 512;

#define FR(buf, kb) (*(const f16x8*)((buf) + hrow + (((kb) * 64 + g * 16) ^ hswz)))
#define STEP_BAR() do { \
        asm volatile("s_waitcnt lgkmcnt(0)" ::: "memory"); \
        __builtin_amdgcn_s_barrier(); \
    } while (0)

    if (wg < 16) {
        // ================= PRODUCER =================
        const int brow = wg * 16 + q;
        const size_t prow = (size_t)brow * 512;
        f16x8 wA[2][8], wP[2][8];
#pragma unroll
        for (int tt = 0; tt < 2; ++tt) {
            const int n = ncol + tt * 16 + q;
#pragma unroll
            for (int kb = 0; kb < 8; ++kb) {
                const int o = n * H_ + kb * 32 + g * 8;
                wA[tt][kb] = cvt8(*(const float4*)(Whh0 + o), *(const float4*)(Whh0 + o + 4));
                wP[tt][kb] = cvt8(*(const float4*)(Wih1 + o), *(const float4*)(Wih1 + o + 4));
            }
        }
#pragma unroll
        for (int tt = 0; tt < 2; ++tt)
#pragma unroll
            for (int kb = 0; kb < 8; ++kb)
                asm volatile("" : "+v"(wA[tt][kb]), "+v"(wP[tt][kb]));
        f32x4 bs1[2];
#pragma unroll
        for (int tt = 0; tt < 2; ++tt) {
            const int n = ncol + tt * 16 + g * 4;
            float4 x = *(const float4*)(bih1 + n);
            float4 y = *(const float4*)(bhh1 + n);
            bs1[tt][0] = x.x + y.x; bs1[tt][1] = x.y + y.y;
            bs1[tt][2] = x.z + y.z; bs1[tt][3] = x.w + y.w;
        }
        {   f32x4 z = {0.f, 0.f, 0.f, 0.f}; *(f32x4*)(hb[1] + tid * 16) = z; }
        const int* idxr = idx + brow * S_;
        int* myflag = flags + wg * 8 + w;
        f16x4 xa[2], xb[2];
        {
            const size_t r0 = (size_t)idxr[0] * H_, r1 = (size_t)idxr[1] * H_;
#pragma unroll
            for (int tt = 0; tt < 2; ++tt) {
                xa[tt] = *(const f16x4*)(T + r0 + ncol + tt * 16 + g * 4);
                xb[tt] = *(const f16x4*)(T + r1 + ncol + tt * 16 + g * 4);
            }
        }
        int idA = idxr[2], idB = idxr[3];
        __syncthreads();

#define PBODY(XV, ID, RD, WR, T_) do {                                          \
        f32x4 a0[2], pP[2];                                                     \
        _Pragma("unroll")                                                       \
        for (int tt = 0; tt < 2; ++tt) {                                        \
            a0[tt][0] = (float)XV[tt][0]; a0[tt][1] = (float)XV[tt][1];         \
            a0[tt][2] = (float)XV[tt][2]; a0[tt][3] = (float)XV[tt][3];         \
            pP[tt] = bs1[tt];                                                   \
        }                                                                       \
        {                                                                       \
            const size_t rr = (size_t)ID * H_;                                  \
            _Pragma("unroll")                                                   \
            for (int tt = 0; tt < 2; ++tt)                                      \
                XV[tt] = *(const f16x4*)(T + rr + ncol + tt * 16 + g * 4);      \
            const int t4 = ((T_) + 4 < S_) ? ((T_) + 4) : (S_ - 1);             \
            ID = idxr[t4];                                                      \
        }                                                                       \
        _Pragma("unroll")                                                       \
        for (int kb = 0; kb < 8; ++kb) {                                        \
            f16x8 bf = FR(RD, kb);                                              \
            a0[0] = MFMA(wA[0][kb], bf, a0[0]);                                 \
            a0[1] = MFMA(wA[1][kb], bf, a0[1]);                                 \
            pP[0] = MFMA(wP[0][kb], bf, pP[0]);                                 \
            pP[1] = MFMA(wP[1][kb], bf, pP[1]);                                 \
        }                                                                       \
        _Pragma("unroll")                                                       \
        for (int tt = 0; tt < 2; ++tt) {                                        \
            f16x4 hv;                                                           \
            _Pragma("unroll")                                                   \
            for (int r = 0; r < 4; ++r) hv[r] = (f16)fast_tanh(a0[tt][r]);      \
            *(f16x4*)(WR + hrow + (((ncol + tt * 16 + g * 4) * 2) ^ hswz)) = hv;\
            f16x4 pv;                                                           \
            _Pragma("unroll")                                                   \
            for (int r = 0; r < 4; ++r) pv[r] = (f16)pP[tt][r];                 \
            *(f16x4*)(pbuf + (prow + (T_) - 1) * 256 + ncol + tt * 16 + g * 4) = pv; \
        }                                                                       \
        if (((T_) & 3) == 0) {                                                  \
            if (lane == 0)                                                      \
                __hip_atomic_store(myflag, (T_), __ATOMIC_RELEASE,              \
                                   __HIP_MEMORY_SCOPE_AGENT);                   \
        }                                                                       \
        STEP_BAR();                                                             \
    } while (0)

        // peel t=0: A-chain only (h0_0 from zeros), reissue xa <- x_2
        {
            f32x4 a0[2];
#pragma unroll
            for (int tt = 0; tt < 2; ++tt) {
                a0[tt][0] = (float)xa[tt][0]; a0[tt][1] = (float)xa[tt][1];
                a0[tt][2] = (float)xa[tt][2]; a0[tt][3] = (float)xa[tt][3];
            }
            {
                const size_t rr = (size_t)idA * H_;
#pragma unroll
                for (int tt = 0; tt < 2; ++tt)
                    xa[tt] = *(const f16x4*)(T + rr + ncol + tt * 16 + g * 4);
                idA = idxr[4];
            }
#pragma unroll
            for (int kb = 0; kb < 8; ++kb) {
                f16x8 bf = FR(hb[1], kb);
                a0[0] = MFMA(wA[0][kb], bf, a0[0]);
                a0[1] = MFMA(wA[1][kb], bf, a0[1]);
            }
#pragma unroll
            for (int tt = 0; tt < 2; ++tt) {
                f16x4 hv;
#pragma unroll
                for (int r = 0; r < 4; ++r) hv[r] = (f16)fast_tanh(a0[tt][r]);
                *(f16x4*)(hb[0] + hrow + (((ncol + tt * 16 + g * 4) * 2) ^ hswz)) = hv;
            }
            STEP_BAR();
        }
        // main: T_ = 1..510 in parity pairs, then 511
        for (int t = 1; t < 511; t += 2) {
            PBODY(xb, idB, hb[0], hb[1], t);
            PBODY(xa, idA, hb[1], hb[0], t + 1);
        }
        PBODY(xb, idB, hb[0], hb[1], 511);
        // peel T_=512: p_511 from h0_511 (in hb[1])
        {
            f32x4 pP[2];
#pragma unroll
            for (int tt = 0; tt < 2; ++tt) pP[tt] = bs1[tt];
#pragma unroll
            for (int kb = 0; kb < 8; ++kb) {
                f16x8 bf = FR(hb[1], kb);
                pP[0] = MFMA(wP[0][kb], bf, pP[0]);
                pP[1] = MFMA(wP[1][kb], bf, pP[1]);
            }
#pragma unroll
            for (int tt = 0; tt < 2; ++tt) {
                f16x4 pv;
#pragma unroll
                for (int r = 0; r < 4; ++r) pv[r] = (f16)pP[tt][r];
                *(f16x4*)(pbuf + (prow + 511) * 256 + ncol + tt * 16 + g * 4) = pv;
            }
        }
        if (lane == 0)
            __hip_atomic_store(myflag, 512, __ATOMIC_RELEASE, __HIP_MEMORY_SCOPE_AGENT);
#undef PBODY
    } else {
        // ================= CONSUMER =================
        const int pr = wg - 16;
        const int brow = pr * 16 + q;
        const size_t prow = (size_t)brow * 512;
        f16x8 wC[2][8];
#pragma unroll
        for (int tt = 0; tt < 2; ++tt) {
            const int n = ncol + tt * 16 + q;
#pragma unroll
            for (int kb = 0; kb < 8; ++kb) {
                const int o = n * H_ + kb * 32 + g * 8;
                wC[tt][kb] = cvt8(*(const float4*)(Whh1 + o), *(const float4*)(Whh1 + o + 4));
            }
        }
#pragma unroll
        for (int tt = 0; tt < 2; ++tt)
#pragma unroll
            for (int kb = 0; kb < 8; ++kb)
                asm volatile("" : "+v"(wC[tt][kb]));
        {   f32x4 z = {0.f, 0.f, 0.f, 0.f}; *(f32x4*)(hb[1] + tid * 16) = z; }
        const int* fl = flags + pr * 8;
        __syncthreads();

#define SPIN(need) do {                                                         \
        int mn;                                                                 \
        do {                                                                    \
            mn = 0x7fffffff;                                                    \
            _Pragma("unroll")                                                   \
            for (int i = 0; i < 8; ++i) {                                       \
                int v = __hip_atomic_load(fl + i, __ATOMIC_RELAXED,             \
                                          __HIP_MEMORY_SCOPE_AGENT);            \
                mn = v < mn ? v : mn;                                           \
            }                                                                   \
        } while (mn < (need));                                                  \
        __builtin_amdgcn_fence(__ATOMIC_ACQUIRE, "agent");                      \
    } while (0)

#define CBODY(PV, RD, WR, T_) do {                                              \
        f32x4 pC[2];                                                            \
        _Pragma("unroll")                                                       \
        for (int tt = 0; tt < 2; ++tt) {                                        \
            pC[tt][0] = (float)PV[tt][0]; pC[tt][1] = (float)PV[tt][1];         \
            pC[tt][2] = (float)PV[tt][2]; pC[tt][3] = (float)PV[tt][3];         \
        }                                                                       \
        {                                                                       \
            const int tr = ((T_) + 2 < S_) ? ((T_) + 2) : (S_ - 1);             \
            _Pragma("unroll")                                                   \
            for (int tt = 0; tt < 2; ++tt)                                      \
                PV[tt] = *(const f16x4*)(pbuf + (prow + tr) * 256 + ncol + tt * 16 + g * 4); \
        }                                                                       \
        _Pragma("unroll")                                                       \
        for (int kb = 0; kb < 8; ++kb) {                                        \
            f16x8 cf = FR(RD, kb);                                              \
            pC[0] = MFMA(wC[0][kb], cf, pC[0]);                                 \
            pC[1] = MFMA(wC[1][kb], cf, pC[1]);                                 \
        }                                                                       \
        _Pragma("unroll")                                                       \
        for (int tt = 0; tt < 2; ++tt) {                                        \
            f16x4 hv;                                                           \
            _Pragma("unroll")                                                   \
            for (int r = 0; r < 4; ++r) hv[r] = (f16)fast_tanh(pC[tt][r]);      \
            *(f16x4*)(WR + hrow + (((ncol + tt * 16 + g * 4) * 2) ^ hswz)) = hv;\
            if ((T_) == S_ - 1)                                                 \
                *(f16x4*)(h1out + (size_t)brow * H_ + ncol + tt * 16 + g * 4) = hv; \
        }                                                                       \
        STEP_BAR();                                                             \
    } while (0)

        f16x4 pa[2], pb[2];
        SPIN(6);
        {
#pragma unroll
            for (int tt = 0; tt < 2; ++tt) {
                pa[tt] = *(const f16x4*)(pbuf + (prow + 0) * 256 + ncol + tt * 16 + g * 4);
                pb[tt] = *(const f16x4*)(pbuf + (prow + 1) * 256 + ncol + tt * 16 + g * 4);
            }
        }
        for (int tb = 0; tb < 512; tb += 4) {
            if (tb) {
                const int need = (tb + 6 < 512) ? tb + 6 : 512;
                SPIN(need);
            }
            CBODY(pa, hb[1], hb[0], tb);
            CBODY(pb, hb[0], hb[1], tb + 1);
            CBODY(pa, hb[1], hb[0], tb + 2);
            CBODY(pb, hb[0], hb[1], tb + 3);
        }
#undef CBODY
#undef SPIN
    }
#undef FR
#undef STEP_BAR
}

// ---------------------------------------------------------------------------
// K3: out[b][v] = sum_k h1[b][k] * Wout[v][k] + bout[v].  fp32 out.
// ---------------------------------------------------------------------------
__global__ __launch_bounds__(512) void k_out(
    const f16* __restrict__ h1, const float* __restrict__ Wout,
    const float* __restrict__ bout, float* __restrict__ out)
{
    __shared__ char Hl[256 * 512];
    const int tid = threadIdx.x;
    {
        const int m = tid >> 1, half = tid & 1;
#pragma unroll
        for (int i = 0; i < 16; ++i) {
            const int blk = half * 16 + i;
            f16x8 v = *(const f16x8*)(h1 + m * H_ + blk * 8);
            *(f16x8*)(Hl + m * 512 + ((blk ^ (m & 7)) << 4)) = v;
        }
    }
    __syncthreads();
    const int lane = tid & 63, w = tid >> 6;
    const int q = lane & 15, g = lane >> 4;
    const int v0 = blockIdx.x * 80;
    f32x4 acc[5][2];
#pragma unroll
    for (int vt = 0; vt < 5; ++vt) {
        float4 bo = *(const float4*)(bout + v0 + vt * 16 + g * 4);
#pragma unroll
        for (int bt = 0; bt < 2; ++bt) {
            acc[vt][bt][0] = bo.x; acc[vt][bt][1] = bo.y;
            acc[vt][bt][2] = bo.z; acc[vt][bt][3] = bo.w;
        }
    }
#pragma unroll
    for (int kb = 0; kb < 8; ++kb) {
        f16x8 bf[2];
#pragma unroll
        for (int bt = 0; bt < 2; ++bt) {
            const int mrow = (w * 2 + bt) * 16 + q;
            bf[bt] = *(const f16x8*)(Hl + mrow * 512 + (((kb * 4 + g) ^ (mrow & 7)) << 4));
        }
#pragma unroll
        for (int vt = 0; vt < 5; ++vt) {
            const size_t vrow = v0 + vt * 16 + q;
            float4 a = *(const float4*)(Wout + vrow * H_ + kb * 32 + g * 8);
            float4 b = *(const float4*)(Wout + vrow * H_ + kb * 32 + g * 8 + 4);
            f16x8 af = cvt8(a, b);
#pragma unroll
            for (int bt = 0; bt < 2; ++bt)
                acc[vt][bt] = MFMA(af, bf[bt], acc[vt][bt]);
        }
    }
#pragma unroll
    for (int vt = 0; vt < 5; ++vt)
#pragma unroll
        for (int bt = 0; bt < 2; ++bt) {
            const int b = (w * 2 + bt) * 16 + q;
            const int v = v0 + vt * 16 + g * 4;
            float4 o = {acc[vt][bt][0], acc[vt][bt][1], acc[vt][bt][2], acc[vt][bt][3]};
            *(float4*)(out + (size_t)b * V_ + v) = o;
        }
}

extern "C" void kernel_launch(void* const* d_in, const int* in_sizes, int n_in,
                              void* d_out, int out_size, void* d_ws, size_t ws_size,
                              hipStream_t stream) {
    (void)in_sizes; (void)n_in; (void)out_size; (void)ws_size;
    const int*   batch = (const int*)  d_in[0];
    const float* feat  = (const float*)d_in[1];
    const float* Wih0  = (const float*)d_in[2];
    const float* Whh0  = (const float*)d_in[3];
    const float* bih0  = (const float*)d_in[4];
    const float* bhh0  = (const float*)d_in[5];
    const float* Wih1  = (const float*)d_in[6];
    const float* Whh1  = (const float*)d_in[7];
    const float* bih1  = (const float*)d_in[8];
    const float* bhh1  = (const float*)d_in[9];
    const float* Wout  = (const float*)d_in[10];
    const float* bout  = (const float*)d_in[11];
    float* out = (float*)d_out;

    f16* T     = (f16*)d_out;                             // 25.6MB scratch in d_out
    int* flags = (int*)((char*)d_out + 48000000);         // 512B, dead until k_out
    f16* pbuf  = (f16*)d_ws;                              // 67MB: p_t stream
    f16* h1out = (f16*)((char*)d_ws + (size_t)B_ * S_ * H_ * 2);  // 128KB

    k_init_flags<<<dim3(1), dim3(128), 0, stream>>>(flags);
    k_vocab_proj<<<dim3(V_ / 16), dim3(512), 0, stream>>>(feat, Wih0, bih0, bhh0, T);
    k_rnn_split<<<dim3(32), dim3(512), 0, stream>>>(T, batch, Whh0, Wih1, bih1, bhh1,
                                                    Whh1, pbuf, flags, h1out);
    k_out<<<dim3(625), dim3(512), 0, stream>>>(h1out, Wout, bout, out);
}